// Round 8
// baseline (308.634 us; speedup 1.0000x reference)
//
#include <hip/hip_runtime.h>
#include <cstdint>

#define NN 50000
#define NE 600000

typedef unsigned short ushort_t;
typedef __bf16 bf16_t;
typedef __attribute__((ext_vector_type(8))) bf16_t bf16x8;
typedef __attribute__((ext_vector_type(8))) ushort_t ushort8;
typedef __attribute__((ext_vector_type(4))) float f32x4;

// ---- ws layout (float offsets), extent 16,141,472 fl = 64.6 MB (< proven 77 MB) ----
// G    : [NN][4*128] bf16   @ 0           (25.6M ushorts = 12.8M fl)
// Xbf  : [NN][128] bf16     @ 12,800,000  (6.4M ushorts = 3.2M fl)
// cnt  : [NN] i32           @ 16,000,000
// curs : [NN] i32           @ 16,050,000
// bsum/bscan : 128+128 i32  @ 16,100,000 / 16,100,128
// colsum/colsq : 128+128 f32@ 16,100,256 / 16,100,384
// WT   : [128][640] bf16    @ 16,100,512  (81,920 ushorts = 40,960 fl)
#define G_OFF    0ul
#define XBF_OFF  12800000ul
#define CNT_OFF  16000000ul
#define CUR_OFF  16050000ul
#define BSUM_OFF 16100000ul
#define BSCN_OFF 16100128ul
#define CS_OFF   16100256ul
#define CSQ_OFF  16100384ul
#define WT_OFF   16100512ul
// d_out transient: epack [NE] u32 @ 0 (scatter -> gather window; dead before
// k_gemm_f writes out)

__device__ __forceinline__ float2 bf2_to_f2(uint32_t u) {
    float2 r;
    r.x = __uint_as_float(u << 16);         // low ushort  = even col
    r.y = __uint_as_float(u & 0xffff0000u); // high ushort = odd col
    return r;
}

__device__ __forceinline__ ushort_t f2bf(float f) {
    uint32_t u = __float_as_uint(f);
    u = (u + 0x7fffu + ((u >> 16) & 1u)) >> 16;   // RNE
    return (ushort_t)u;
}

__device__ __forceinline__ uint32_t f2bf2(float x, float y) {
    return (uint32_t)f2bf(x) | ((uint32_t)f2bf(y) << 16);
}

// ---------------------------------------------------------------------------
// K0: WT[n][kk] bf16, kk<128 -> Wl[kk][n]; kk>=128: j=kk-128 (=b*128+i) ->
// bases[b][i][n].  So B-col n, K-order matches A = [x | g] with g=[4][128].
// ---------------------------------------------------------------------------
__global__ __launch_bounds__(256) void k_prep(
    const float* __restrict__ Wl, const float* __restrict__ bases,
    ushort_t* __restrict__ WT)
{
    const int i = blockIdx.x * 256 + threadIdx.x;
    if (i >= 128 * 640) return;
    const int n = i / 640;
    const int kk = i - n * 640;
    float v;
    if (kk < 128) v = Wl[kk * 128 + n];
    else {
        const int j = kk - 128;
        v = bases[(size_t)(j >> 7) * 16384 + (j & 127) * 128 + n];
    }
    WT[i] = f2bf(v);
}

// ---------------------------------------------------------------------------
// K0b: Xbf = bf16(X). 8 floats/thread.
// ---------------------------------------------------------------------------
__global__ __launch_bounds__(256) void k_cast(
    const float* __restrict__ X, ushort_t* __restrict__ Xbf)
{
    const int i = blockIdx.x * 256 + threadIdx.x;   // group of 8
    if (i >= NN * 16) return;
    const float4* p = (const float4*)(X + (size_t)i * 8);
    const float4 a = p[0], b = p[1];
    ushort_t t8[8] = { f2bf(a.x), f2bf(a.y), f2bf(a.z), f2bf(a.w),
                       f2bf(b.x), f2bf(b.y), f2bf(b.z), f2bf(b.w) };
    *(uint4*)(Xbf + (size_t)i * 8) = *(const uint4*)t8;
}

// ---------------------------------------------------------------------------
// K2: histogram of dst -> cnt
// ---------------------------------------------------------------------------
__global__ __launch_bounds__(256) void k_hist(
    const int* __restrict__ eidx, int* __restrict__ cnt)
{
    const int* __restrict__ dst = eidx + NE;
    for (int e = blockIdx.x * 256 + threadIdx.x; e < NE; e += gridDim.x * 256)
        atomicAdd(cnt + dst[e], 1);
}

// ---------------------------------------------------------------------------
// K3a/b/c: exclusive scan of cnt -> curs
// ---------------------------------------------------------------------------
__global__ __launch_bounds__(256) void k_scan1(
    const int* __restrict__ cnt, int* __restrict__ curs, int* __restrict__ bsum)
{
    __shared__ int sh[256];
    const int tid = threadIdx.x;
    const int i0 = blockIdx.x * 512 + tid * 2;
    const int v0 = (i0 < NN) ? cnt[i0] : 0;
    const int v1 = (i0 + 1 < NN) ? cnt[i0 + 1] : 0;
    int s = v0 + v1;
    sh[tid] = s;
    __syncthreads();
#pragma unroll
    for (int off = 1; off < 256; off <<= 1) {
        int t = (tid >= off) ? sh[tid - off] : 0;
        __syncthreads();
        sh[tid] += t;
        __syncthreads();
    }
    const int excl = sh[tid] - s;
    if (i0 < NN) curs[i0] = excl;
    if (i0 + 1 < NN) curs[i0 + 1] = excl + v0;
    if (tid == 255) bsum[blockIdx.x] = sh[255];
}

__global__ __launch_bounds__(128) void k_scan2(
    const int* __restrict__ bsum, int* __restrict__ bscan, int nblk)
{
    __shared__ int sh[128];
    const int tid = threadIdx.x;
    int v = (tid < nblk) ? bsum[tid] : 0;
    sh[tid] = v;
    __syncthreads();
#pragma unroll
    for (int off = 1; off < 128; off <<= 1) {
        int t = (tid >= off) ? sh[tid - off] : 0;
        __syncthreads();
        sh[tid] += t;
        __syncthreads();
    }
    if (tid < nblk) bscan[tid] = sh[tid] - v;
}

__global__ __launch_bounds__(256) void k_scan3(
    int* __restrict__ curs, const int* __restrict__ bscan)
{
    const int add = bscan[blockIdx.x];
    const int i0 = blockIdx.x * 512 + threadIdx.x * 2;
    if (i0 < NN) curs[i0] += add;
    if (i0 + 1 < NN) curs[i0 + 1] += add;
}

// ---------------------------------------------------------------------------
// K4: scatter edges into CSR slots. epack = src | (type<<16).
// ---------------------------------------------------------------------------
__global__ __launch_bounds__(256) void k_scatter(
    const int* __restrict__ eidx, const int* __restrict__ etype,
    int* __restrict__ curs, uint32_t* __restrict__ epack)
{
    const int* __restrict__ src = eidx;
    const int* __restrict__ dst = eidx + NE;
    for (int e = blockIdx.x * 256 + threadIdx.x; e < NE; e += gridDim.x * 256) {
        const int d = dst[e];
        const int pos = atomicAdd(curs + d, 1);
        epack[pos] = (uint32_t)src[e] | ((uint32_t)etype[e] << 16);
    }
}

// ---------------------------------------------------------------------------
// K5: gather raw X rows (256 B/edge): G_b[d] = sum_{e->d} c[t_e,b]*xbf[src_e].
// ---------------------------------------------------------------------------
__device__ __forceinline__ void edge_accum(
    uint32_t ep, const ushort_t* __restrict__ Xbf,
    const float* __restrict__ coeff, int lane,
    float2& m0, float2& m1, float2& m2, float2& m3)
{
    const int s = ep & 0xffff;
    const int t = ep >> 16;
    const float4 cw = *(const float4*)(coeff + t * 4);
    const uint32_t xv = *(const uint32_t*)(Xbf + (size_t)s * 128 + lane * 2);
    const float2 x = bf2_to_f2(xv);
    m0.x += cw.x * x.x; m0.y += cw.x * x.y;
    m1.x += cw.y * x.x; m1.y += cw.y * x.y;
    m2.x += cw.z * x.x; m2.y += cw.z * x.y;
    m3.x += cw.w * x.x; m3.y += cw.w * x.y;
}

__global__ __launch_bounds__(256) void k_gather(
    const ushort_t* __restrict__ Xbf, const uint32_t* __restrict__ epack,
    const int* __restrict__ cnt, const int* __restrict__ curs,
    const float* __restrict__ coeff, ushort_t* __restrict__ G)
{
    const int lane = threadIdx.x & 63;
    const int d = (blockIdx.x * 256 + threadIdx.x) >> 6;
    if (d >= NN) return;

    const int n = cnt[d];
    const int end = curs[d];          // post-scatter: end offset
    int j = end - n;

    float2 m0 = {0.f, 0.f}, m1 = {0.f, 0.f}, m2 = {0.f, 0.f}, m3 = {0.f, 0.f};
    for (; j + 3 < end; j += 4) {
        const uint32_t e0 = epack[j];
        const uint32_t e1 = epack[j + 1];
        const uint32_t e2 = epack[j + 2];
        const uint32_t e3 = epack[j + 3];
        edge_accum(e0, Xbf, coeff, lane, m0, m1, m2, m3);
        edge_accum(e1, Xbf, coeff, lane, m0, m1, m2, m3);
        edge_accum(e2, Xbf, coeff, lane, m0, m1, m2, m3);
        edge_accum(e3, Xbf, coeff, lane, m0, m1, m2, m3);
    }
    for (; j < end; ++j) edge_accum(epack[j], Xbf, coeff, lane, m0, m1, m2, m3);

    uint32_t* gp = (uint32_t*)(G + (size_t)d * 512) + lane;
    gp[0]   = f2bf2(m0.x, m0.y);
    gp[64]  = f2bf2(m1.x, m1.y);
    gp[128] = f2bf2(m2.x, m2.y);
    gp[192] = f2bf2(m3.x, m3.y);
}

// ---------------------------------------------------------------------------
// K6: FUSED projection. out[d] = ([Xbf[d] | G[d]] @ WT^T + bl) / deg[d],
// plus per-column sum/sumsq (shfl-reduced, 1 atomic per col per block).
// 16x16x32 layouts: A m=lane&15,k=quad*8+j; B n=lane&15,k=quad*8+j;
// D col=lane&15, row=quad*4+reg.
// Block = 64 rows x 64 cols, grid (782, 2); wave = one 16-col tile, K=640:
// 20 B-frags register-resident (launch_bounds(256,2) permits ~256 VGPR).
// ---------------------------------------------------------------------------
__global__ __launch_bounds__(256, 2) void k_gemm_f(
    const ushort_t* __restrict__ Xbf, const ushort_t* __restrict__ G,
    const ushort_t* __restrict__ WT, const float* __restrict__ bl,
    const int* __restrict__ cnt, float* __restrict__ out,
    float* __restrict__ colsum, float* __restrict__ colsq)
{
    const int tid = threadIdx.x;
    const int row0 = blockIdx.x * 64;
    const int ch = blockIdx.y;           // col half
    const int lane = tid & 63;
    const int w = tid >> 6;
    const int m = lane & 15;
    const int quad = lane >> 4;
    const int col = ch * 64 + w * 16 + m;

    // B register-resident: 20 K-chunks of 32
    bf16x8 bfrag[20];
    {
        const ushort_t* bp = WT + (size_t)col * 640 + quad * 8;
#pragma unroll
        for (int kc = 0; kc < 20; ++kc)
            bfrag[kc] = __builtin_bit_cast(bf16x8, *(const ushort8*)(bp + kc * 32));
    }
    const float blv = bl[col];

    float s = 0.f, q = 0.f;

    for (int chunk = 0; chunk < 4; ++chunk) {
        int arow = row0 + chunk * 16 + m;
        if (arow >= NN) arow = NN - 1;   // clamp; stores/stats guarded
        const ushort_t* ax = Xbf + (size_t)arow * 128 + quad * 8;
        const ushort_t* ag = G + (size_t)arow * 512 + quad * 8;

        bf16x8 afrag[20];
#pragma unroll
        for (int kc = 0; kc < 4; ++kc)
            afrag[kc] = __builtin_bit_cast(bf16x8, *(const ushort8*)(ax + kc * 32));
#pragma unroll
        for (int kc = 0; kc < 16; ++kc)
            afrag[4 + kc] = __builtin_bit_cast(bf16x8, *(const ushort8*)(ag + kc * 32));

        f32x4 c;
#pragma unroll
        for (int i = 0; i < 4; ++i) c[i] = 0.f;
#pragma unroll
        for (int kc = 0; kc < 20; ++kc)
            c = __builtin_amdgcn_mfma_f32_16x16x32_bf16(afrag[kc], bfrag[kc], c, 0, 0, 0);

        const int rowb = row0 + chunk * 16 + quad * 4;
#pragma unroll
        for (int r = 0; r < 4; ++r) {
            const int row = rowb + r;
            if (row < NN) {
                const int dg = cnt[row];
                const float inv = 1.0f / (float)((dg > 0) ? dg : 1);
                const float v = (c[r] + blv) * inv;
                out[(size_t)row * 128 + col] = v;
                s += v; q += v * v;
            }
        }
    }

    // reduce over quads: lanes {m, m+16, m+32, m+48} -> lane m
    s += __shfl_down(s, 32); q += __shfl_down(q, 32);
    s += __shfl_down(s, 16); q += __shfl_down(q, 16);
    if (lane < 16) {
        atomicAdd(colsum + col, s);
        atomicAdd(colsq + col, q);
    }
}

// ---------------------------------------------------------------------------
// K7: BatchNorm (batch stats) + ReLU, in place on d_out.
// ---------------------------------------------------------------------------
__global__ __launch_bounds__(256) void k_bn_relu(
    float* __restrict__ out, const float* __restrict__ colsum,
    const float* __restrict__ colsq, const float* __restrict__ gamma,
    const float* __restrict__ beta)
{
    __shared__ float sc[128], sh[128];
    const int tid = threadIdx.x;
    if (tid < 128) {
        const float mean = colsum[tid] * (1.0f / NN);
        const float var = colsq[tid] * (1.0f / NN) - mean * mean;
        const float g = gamma[tid] * rsqrtf(var + 1e-5f);
        sc[tid] = g;
        sh[tid] = beta[tid] - mean * g;
    }
    __syncthreads();
    const int total = NN * 32;
    for (int i = blockIdx.x * 256 + tid; i < total; i += gridDim.x * 256) {
        const int c = (i & 31) << 2;
        float4 v = *(float4*)(out + (size_t)i * 4);
        v.x = fmaxf(fmaf(v.x, sc[c + 0], sh[c + 0]), 0.f);
        v.y = fmaxf(fmaf(v.y, sc[c + 1], sh[c + 1]), 0.f);
        v.z = fmaxf(fmaf(v.z, sc[c + 2], sh[c + 2]), 0.f);
        v.w = fmaxf(fmaf(v.w, sc[c + 3], sh[c + 3]), 0.f);
        *(float4*)(out + (size_t)i * 4) = v;
    }
}

extern "C" void kernel_launch(void* const* d_in, const int* in_sizes, int n_in,
                              void* d_out, int out_size, void* d_ws, size_t ws_size,
                              hipStream_t stream)
{
    const float* X      = (const float*)d_in[0];
    const float* bases  = (const float*)d_in[1];
    const float* coeff  = (const float*)d_in[2];
    const float* Wl     = (const float*)d_in[3];
    const float* bl     = (const float*)d_in[4];
    const float* gamma  = (const float*)d_in[5];
    const float* beta   = (const float*)d_in[6];
    const int*   eidx   = (const int*)d_in[7];
    const int*   etype  = (const int*)d_in[8];
    float* out = (float*)d_out;

    float* ws = (float*)d_ws;
    ushort_t* G      = (ushort_t*)(ws + G_OFF);
    ushort_t* Xbf    = (ushort_t*)(ws + XBF_OFF);
    int*      cnt    = (int*)(ws + CNT_OFF);
    int*      curs   = (int*)(ws + CUR_OFF);
    int*      bsum   = (int*)(ws + BSUM_OFF);
    int*      bscan  = (int*)(ws + BSCN_OFF);
    float*    colsum = ws + CS_OFF;
    float*    colsq  = ws + CSQ_OFF;
    ushort_t* WT     = (ushort_t*)(ws + WT_OFF);
    uint32_t* epack  = (uint32_t*)d_out;   // dead before k_gemm_f writes out

    // zero cnt, curs, bsum, bscan, colsum, colsq
    hipMemsetAsync(cnt, 0, (CSQ_OFF + 128 - CNT_OFF) * sizeof(float), stream);

    const int nblk_scan = (NN + 511) / 512;   // 98

    k_prep<<<(128 * 640 + 255) / 256, 256, 0, stream>>>(Wl, bases, WT);
    k_cast<<<(NN * 16 + 255) / 256, 256, 0, stream>>>(X, Xbf);
    k_hist<<<512, 256, 0, stream>>>(eidx, cnt);
    k_scan1<<<nblk_scan, 256, 0, stream>>>(cnt, curs, bsum);
    k_scan2<<<1, 128, 0, stream>>>(bsum, bscan, nblk_scan);
    k_scan3<<<nblk_scan, 256, 0, stream>>>(curs, bscan);
    k_scatter<<<512, 256, 0, stream>>>(eidx, etype, curs, epack);
    k_gather<<<(NN + 3) / 4, 256, 0, stream>>>(Xbf, epack, cnt, curs, coeff, G);
    k_gemm_f<<<dim3((NN + 63) / 64, 2), 256, 0, stream>>>(
        Xbf, G, WT, bl, cnt, out, colsum, colsq);
    k_bn_relu<<<1024, 256, 0, stream>>>(out, colsum, colsq, gamma, beta);
}

// Round 9
// 292.085 us; speedup vs baseline: 1.0567x; 1.0567x over previous
//
#include <hip/hip_runtime.h>
#include <cstdint>

#define NN 50000
#define NE 600000

typedef unsigned short ushort_t;
typedef __bf16 bf16_t;
typedef __attribute__((ext_vector_type(8))) bf16_t bf16x8;
typedef __attribute__((ext_vector_type(8))) ushort_t ushort8;
typedef __attribute__((ext_vector_type(4))) float f32x4;

// ---- ws layout (float offsets), extent 16,141,472 fl = 64.6 MB ----
// G    : [NN][4*128] bf16   @ 0           (25.6M ushorts = 12.8M fl)
// Xbf  : [NN][128] bf16     @ 12,800,000  (6.4M ushorts = 3.2M fl)
// cnt  : [NN] i32           @ 16,000,000
// curs : [NN] i32           @ 16,050,000
// bsum/bscan : 128+128 i32  @ 16,100,000 / 16,100,128
// colsum/colsq : 128+128 f32@ 16,100,256 / 16,100,384
// WT   : [128][640] bf16    @ 16,100,512
#define G_OFF    0ul
#define XBF_OFF  12800000ul
#define CNT_OFF  16000000ul
#define CUR_OFF  16050000ul
#define BSUM_OFF 16100000ul
#define BSCN_OFF 16100128ul
#define CS_OFF   16100256ul
#define CSQ_OFF  16100384ul
#define WT_OFF   16100512ul
// d_out transient: epack [NE] u32 @ 0 (scatter -> gather; dead before k_gemm_f)

__device__ __forceinline__ float2 bf2_to_f2(uint32_t u) {
    float2 r;
    r.x = __uint_as_float(u << 16);
    r.y = __uint_as_float(u & 0xffff0000u);
    return r;
}

__device__ __forceinline__ ushort_t f2bf(float f) {
    uint32_t u = __float_as_uint(f);
    u = (u + 0x7fffu + ((u >> 16) & 1u)) >> 16;   // RNE
    return (ushort_t)u;
}

__device__ __forceinline__ uint32_t f2bf2(float x, float y) {
    return (uint32_t)f2bf(x) | ((uint32_t)f2bf(y) << 16);
}

// XOR-swizzle of 16B-group index g (0..79) by low-3 bits of row r:
// permutes within aligned 8-group windows; same fn on store & load sides.
__device__ __forceinline__ int swz(int g, int r) {
    return (g & 0x78) | ((g ^ r) & 7);
}

// ---------------------------------------------------------------------------
// K0: WT[n][kk] bf16; kk<128 -> Wl[kk][n]; kk>=128: j=kk-128 (=b*128+i) ->
// bases[b][i][n].  K-order matches A = [x | g], g = [4][128].
// ---------------------------------------------------------------------------
__global__ __launch_bounds__(256) void k_prep(
    const float* __restrict__ Wl, const float* __restrict__ bases,
    ushort_t* __restrict__ WT)
{
    const int i = blockIdx.x * 256 + threadIdx.x;
    if (i >= 128 * 640) return;
    const int n = i / 640;
    const int kk = i - n * 640;
    float v;
    if (kk < 128) v = Wl[kk * 128 + n];
    else {
        const int j = kk - 128;
        v = bases[(size_t)(j >> 7) * 16384 + (j & 127) * 128 + n];
    }
    WT[i] = f2bf(v);
}

// ---------------------------------------------------------------------------
// K0b: Xbf = bf16(X). 8 floats/thread.
// ---------------------------------------------------------------------------
__global__ __launch_bounds__(256) void k_cast(
    const float* __restrict__ X, ushort_t* __restrict__ Xbf)
{
    const int i = blockIdx.x * 256 + threadIdx.x;
    if (i >= NN * 16) return;
    const float4* p = (const float4*)(X + (size_t)i * 8);
    const float4 a = p[0], b = p[1];
    ushort_t t8[8] = { f2bf(a.x), f2bf(a.y), f2bf(a.z), f2bf(a.w),
                       f2bf(b.x), f2bf(b.y), f2bf(b.z), f2bf(b.w) };
    *(uint4*)(Xbf + (size_t)i * 8) = *(const uint4*)t8;
}

// ---------------------------------------------------------------------------
// K2: histogram of dst -> cnt
// ---------------------------------------------------------------------------
__global__ __launch_bounds__(256) void k_hist(
    const int* __restrict__ eidx, int* __restrict__ cnt)
{
    const int* __restrict__ dst = eidx + NE;
    for (int e = blockIdx.x * 256 + threadIdx.x; e < NE; e += gridDim.x * 256)
        atomicAdd(cnt + dst[e], 1);
}

// ---------------------------------------------------------------------------
// K3a/b/c: exclusive scan of cnt -> curs
// ---------------------------------------------------------------------------
__global__ __launch_bounds__(256) void k_scan1(
    const int* __restrict__ cnt, int* __restrict__ curs, int* __restrict__ bsum)
{
    __shared__ int sh[256];
    const int tid = threadIdx.x;
    const int i0 = blockIdx.x * 512 + tid * 2;
    const int v0 = (i0 < NN) ? cnt[i0] : 0;
    const int v1 = (i0 + 1 < NN) ? cnt[i0 + 1] : 0;
    int s = v0 + v1;
    sh[tid] = s;
    __syncthreads();
#pragma unroll
    for (int off = 1; off < 256; off <<= 1) {
        int t = (tid >= off) ? sh[tid - off] : 0;
        __syncthreads();
        sh[tid] += t;
        __syncthreads();
    }
    const int excl = sh[tid] - s;
    if (i0 < NN) curs[i0] = excl;
    if (i0 + 1 < NN) curs[i0 + 1] = excl + v0;
    if (tid == 255) bsum[blockIdx.x] = sh[255];
}

__global__ __launch_bounds__(128) void k_scan2(
    const int* __restrict__ bsum, int* __restrict__ bscan, int nblk)
{
    __shared__ int sh[128];
    const int tid = threadIdx.x;
    int v = (tid < nblk) ? bsum[tid] : 0;
    sh[tid] = v;
    __syncthreads();
#pragma unroll
    for (int off = 1; off < 128; off <<= 1) {
        int t = (tid >= off) ? sh[tid - off] : 0;
        __syncthreads();
        sh[tid] += t;
        __syncthreads();
    }
    if (tid < nblk) bscan[tid] = sh[tid] - v;
}

__global__ __launch_bounds__(256) void k_scan3(
    int* __restrict__ curs, const int* __restrict__ bscan)
{
    const int add = bscan[blockIdx.x];
    const int i0 = blockIdx.x * 512 + threadIdx.x * 2;
    if (i0 < NN) curs[i0] += add;
    if (i0 + 1 < NN) curs[i0 + 1] += add;
}

// ---------------------------------------------------------------------------
// K4: scatter edges into CSR slots. epack = src | (type<<16).
// ---------------------------------------------------------------------------
__global__ __launch_bounds__(256) void k_scatter(
    const int* __restrict__ eidx, const int* __restrict__ etype,
    int* __restrict__ curs, uint32_t* __restrict__ epack)
{
    const int* __restrict__ src = eidx;
    const int* __restrict__ dst = eidx + NE;
    for (int e = blockIdx.x * 256 + threadIdx.x; e < NE; e += gridDim.x * 256) {
        const int d = dst[e];
        const int pos = atomicAdd(curs + d, 1);
        epack[pos] = (uint32_t)src[e] | ((uint32_t)etype[e] << 16);
    }
}

// ---------------------------------------------------------------------------
// K5: gather raw X rows (256 B/edge): G_b[d] = sum_{e->d} c[t_e,b]*xbf[src_e].
// ---------------------------------------------------------------------------
__device__ __forceinline__ void edge_accum(
    uint32_t ep, const ushort_t* __restrict__ Xbf,
    const float* __restrict__ coeff, int lane,
    float2& m0, float2& m1, float2& m2, float2& m3)
{
    const int s = ep & 0xffff;
    const int t = ep >> 16;
    const float4 cw = *(const float4*)(coeff + t * 4);
    const uint32_t xv = *(const uint32_t*)(Xbf + (size_t)s * 128 + lane * 2);
    const float2 x = bf2_to_f2(xv);
    m0.x += cw.x * x.x; m0.y += cw.x * x.y;
    m1.x += cw.y * x.x; m1.y += cw.y * x.y;
    m2.x += cw.z * x.x; m2.y += cw.z * x.y;
    m3.x += cw.w * x.x; m3.y += cw.w * x.y;
}

__global__ __launch_bounds__(256) void k_gather(
    const ushort_t* __restrict__ Xbf, const uint32_t* __restrict__ epack,
    const int* __restrict__ cnt, const int* __restrict__ curs,
    const float* __restrict__ coeff, ushort_t* __restrict__ G)
{
    const int lane = threadIdx.x & 63;
    const int d = (blockIdx.x * 256 + threadIdx.x) >> 6;
    if (d >= NN) return;

    const int n = cnt[d];
    const int end = curs[d];
    int j = end - n;

    float2 m0 = {0.f, 0.f}, m1 = {0.f, 0.f}, m2 = {0.f, 0.f}, m3 = {0.f, 0.f};
    for (; j + 3 < end; j += 4) {
        const uint32_t e0 = epack[j];
        const uint32_t e1 = epack[j + 1];
        const uint32_t e2 = epack[j + 2];
        const uint32_t e3 = epack[j + 3];
        edge_accum(e0, Xbf, coeff, lane, m0, m1, m2, m3);
        edge_accum(e1, Xbf, coeff, lane, m0, m1, m2, m3);
        edge_accum(e2, Xbf, coeff, lane, m0, m1, m2, m3);
        edge_accum(e3, Xbf, coeff, lane, m0, m1, m2, m3);
    }
    for (; j < end; ++j) edge_accum(epack[j], Xbf, coeff, lane, m0, m1, m2, m3);

    uint32_t* gp = (uint32_t*)(G + (size_t)d * 512) + lane;
    gp[0]   = f2bf2(m0.x, m0.y);
    gp[64]  = f2bf2(m1.x, m1.y);
    gp[128] = f2bf2(m2.x, m2.y);
    gp[192] = f2bf2(m3.x, m3.y);
}

// ---------------------------------------------------------------------------
// K6: FUSED projection, A-in-LDS. Block = 32 rows x 128 cols, grid 1563.
// Whole K=640 strip of [Xbf|G] for 32 rows staged once into LDS (40KB,
// XOR-swizzled 16B groups). 4 waves, wave = 32 cols (2 tiles), K fully
// unrolled: per chunk 2 ds_read_b128 (A) + 2 L2-hot 16B loads (B) + 4 MFMA.
// Epilogue folds degree-norm + column sum/sumsq (shfl + 1 atomic/col/block).
// 16x16x32 layouts: A m=lane&15,k=quad*8+j; B n=lane&15,k=quad*8+j;
// D col=lane&15, row=quad*4+reg.
// ---------------------------------------------------------------------------
__global__ __launch_bounds__(256) void k_gemm_f(
    const ushort_t* __restrict__ Xbf, const ushort_t* __restrict__ G,
    const ushort_t* __restrict__ WT, const float* __restrict__ bl,
    const int* __restrict__ cnt, float* __restrict__ out,
    float* __restrict__ colsum, float* __restrict__ colsq)
{
    __shared__ ushort_t As[32][648];   // [row][kk], 16B groups swizzled
    const int tid = threadIdx.x;
    const int row0 = blockIdx.x * 32;

    // ---- stage: 32 rows x 640 bf16. 8 threads/row, 10 x 16B each. ----
    {
        const int r = tid >> 3;        // 0..31
        const int t = tid & 7;         // 0..7
        const int srow = row0 + r;     // OOB rows (<50016) read into adjacent
                                       // ws regions -- allocated, garbage ok
        const ushort_t* xs = Xbf + (size_t)srow * 128 + t * 8;
        const ushort_t* gs = G   + (size_t)srow * 512 + t * 8;
#pragma unroll
        for (int c = 0; c < 2; ++c) {
            const uint4 v = *(const uint4*)(xs + c * 64);
            *(uint4*)&As[r][swz(c * 8 + t, r) * 8] = v;
        }
#pragma unroll
        for (int c = 2; c < 10; ++c) {
            const uint4 v = *(const uint4*)(gs + (c - 2) * 64);
            *(uint4*)&As[r][swz(c * 8 + t, r) * 8] = v;
        }
    }
    __syncthreads();

    const int lane = tid & 63;
    const int w = tid >> 6;
    const int m = lane & 15;
    const int quad = lane >> 4;

    const ushort_t* bp0 = WT + (size_t)(w * 32 + m) * 640 + quad * 8;  // ct=0
    const ushort_t* bp1 = bp0 + 16 * 640;                              // ct=1

    f32x4 cc[2][2];
#pragma unroll
    for (int rt = 0; rt < 2; ++rt)
#pragma unroll
        for (int ct = 0; ct < 2; ++ct)
#pragma unroll
            for (int i = 0; i < 4; ++i) cc[rt][ct][i] = 0.f;

#pragma unroll
    for (int chunk = 0; chunk < 20; ++chunk) {
        const bf16x8 b0 = __builtin_bit_cast(bf16x8,
            *(const ushort8*)(bp0 + chunk * 32));
        const bf16x8 b1 = __builtin_bit_cast(bf16x8,
            *(const ushort8*)(bp1 + chunk * 32));
        const int goff = swz(chunk * 4 + quad, m) * 8;   // (row&7)==(m&7)
        const bf16x8 a0 = __builtin_bit_cast(bf16x8,
            *(const ushort8*)&As[m][goff]);
        const bf16x8 a1 = __builtin_bit_cast(bf16x8,
            *(const ushort8*)&As[16 + m][goff]);
        cc[0][0] = __builtin_amdgcn_mfma_f32_16x16x32_bf16(a0, b0, cc[0][0], 0, 0, 0);
        cc[0][1] = __builtin_amdgcn_mfma_f32_16x16x32_bf16(a0, b1, cc[0][1], 0, 0, 0);
        cc[1][0] = __builtin_amdgcn_mfma_f32_16x16x32_bf16(a1, b0, cc[1][0], 0, 0, 0);
        cc[1][1] = __builtin_amdgcn_mfma_f32_16x16x32_bf16(a1, b1, cc[1][1], 0, 0, 0);
    }

    // ---- epilogue: degree-norm, store, column stats ----
    const float blv0 = bl[w * 32 + m];
    const float blv1 = bl[w * 32 + 16 + m];
    float s0 = 0.f, q0 = 0.f, s1 = 0.f, q1 = 0.f;

#pragma unroll
    for (int rt = 0; rt < 2; ++rt) {
        const int rowb = row0 + rt * 16 + quad * 4;
#pragma unroll
        for (int r = 0; r < 4; ++r) {
            const int row = rowb + r;
            if (row < NN) {
                const int dg = cnt[row];
                const float inv = 1.0f / (float)((dg > 0) ? dg : 1);
                float* po = out + (size_t)row * 128 + w * 32 + m;
                const float v0 = (cc[rt][0][r] + blv0) * inv;
                const float v1 = (cc[rt][1][r] + blv1) * inv;
                po[0]  = v0;
                po[16] = v1;
                s0 += v0; q0 += v0 * v0;
                s1 += v1; q1 += v1 * v1;
            }
        }
    }

    // reduce over quads (lanes m, m+16, m+32, m+48 -> lane m)
    s0 += __shfl_down(s0, 32); q0 += __shfl_down(q0, 32);
    s0 += __shfl_down(s0, 16); q0 += __shfl_down(q0, 16);
    s1 += __shfl_down(s1, 32); q1 += __shfl_down(q1, 32);
    s1 += __shfl_down(s1, 16); q1 += __shfl_down(q1, 16);
    if (lane < 16) {
        atomicAdd(colsum + w * 32 + lane, s0);
        atomicAdd(colsq  + w * 32 + lane, q0);
        atomicAdd(colsum + w * 32 + 16 + lane, s1);
        atomicAdd(colsq  + w * 32 + 16 + lane, q1);
    }
}

// ---------------------------------------------------------------------------
// K7: BatchNorm (batch stats) + ReLU, in place on d_out.
// ---------------------------------------------------------------------------
__global__ __launch_bounds__(256) void k_bn_relu(
    float* __restrict__ out, const float* __restrict__ colsum,
    const float* __restrict__ colsq, const float* __restrict__ gamma,
    const float* __restrict__ beta)
{
    __shared__ float sc[128], sh[128];
    const int tid = threadIdx.x;
    if (tid < 128) {
        const float mean = colsum[tid] * (1.0f / NN);
        const float var = colsq[tid] * (1.0f / NN) - mean * mean;
        const float g = gamma[tid] * rsqrtf(var + 1e-5f);
        sc[tid] = g;
        sh[tid] = beta[tid] - mean * g;
    }
    __syncthreads();
    const int total = NN * 32;
    for (int i = blockIdx.x * 256 + tid; i < total; i += gridDim.x * 256) {
        const int c = (i & 31) << 2;
        float4 v = *(float4*)(out + (size_t)i * 4);
        v.x = fmaxf(fmaf(v.x, sc[c + 0], sh[c + 0]), 0.f);
        v.y = fmaxf(fmaf(v.y, sc[c + 1], sh[c + 1]), 0.f);
        v.z = fmaxf(fmaf(v.z, sc[c + 2], sh[c + 2]), 0.f);
        v.w = fmaxf(fmaf(v.w, sc[c + 3], sh[c + 3]), 0.f);
        *(float4*)(out + (size_t)i * 4) = v;
    }
}

extern "C" void kernel_launch(void* const* d_in, const int* in_sizes, int n_in,
                              void* d_out, int out_size, void* d_ws, size_t ws_size,
                              hipStream_t stream)
{
    const float* X      = (const float*)d_in[0];
    const float* bases  = (const float*)d_in[1];
    const float* coeff  = (const float*)d_in[2];
    const float* Wl     = (const float*)d_in[3];
    const float* bl     = (const float*)d_in[4];
    const float* gamma  = (const float*)d_in[5];
    const float* beta   = (const float*)d_in[6];
    const int*   eidx   = (const int*)d_in[7];
    const int*   etype  = (const int*)d_in[8];
    float* out = (float*)d_out;

    float* ws = (float*)d_ws;
    ushort_t* G      = (ushort_t*)(ws + G_OFF);
    ushort_t* Xbf    = (ushort_t*)(ws + XBF_OFF);
    int*      cnt    = (int*)(ws + CNT_OFF);
    int*      curs   = (int*)(ws + CUR_OFF);
    int*      bsum   = (int*)(ws + BSUM_OFF);
    int*      bscan  = (int*)(ws + BSCN_OFF);
    float*    colsum = ws + CS_OFF;
    float*    colsq  = ws + CSQ_OFF;
    ushort_t* WT     = (ushort_t*)(ws + WT_OFF);
    uint32_t* epack  = (uint32_t*)d_out;   // dead before k_gemm_f writes out

    // zero cnt, curs, bsum, bscan, colsum, colsq
    hipMemsetAsync(cnt, 0, (CSQ_OFF + 128 - CNT_OFF) * sizeof(float), stream);

    const int nblk_scan = (NN + 511) / 512;   // 98

    k_prep<<<(128 * 640 + 255) / 256, 256, 0, stream>>>(Wl, bases, WT);
    k_cast<<<(NN * 16 + 255) / 256, 256, 0, stream>>>(X, Xbf);
    k_hist<<<512, 256, 0, stream>>>(eidx, cnt);
    k_scan1<<<nblk_scan, 256, 0, stream>>>(cnt, curs, bsum);
    k_scan2<<<1, 128, 0, stream>>>(bsum, bscan, nblk_scan);
    k_scan3<<<nblk_scan, 256, 0, stream>>>(curs, bscan);
    k_scatter<<<512, 256, 0, stream>>>(eidx, etype, curs, epack);
    k_gather<<<(NN + 3) / 4, 256, 0, stream>>>(Xbf, epack, cnt, curs, coeff, G);
    k_gemm_f<<<(NN + 31) / 32, 256, 0, stream>>>(
        Xbf, G, WT, bl, cnt, out, colsum, colsq);
    k_bn_relu<<<1024, 256, 0, stream>>>(out, colsum, colsq, gamma, beta);
}